// Round 16
// baseline (829.022 us; speedup 1.0000x reference)
//
#include <hip/hip_runtime.h>
#include <hip/hip_bf16.h>
#include <math.h>

typedef unsigned short u16;
typedef unsigned int   u32;
typedef __bf16 bf16x8_t __attribute__((ext_vector_type(8)));
typedef float  f32x4_t  __attribute__((ext_vector_type(4)));

#define DEVI static __device__ __forceinline__

DEVI float bf2f(u16 u){ union{u32 i; float f;} v; v.i = ((u32)u)<<16; return v.f; }
DEVI u16 f2bf(float f){ union{float f; u32 i;} v; v.f = f; u32 i = v.i; i += 0x7fffu + ((i>>16)&1u); return (u16)(i>>16); }
DEVI float sigm(float x){ return 1.0f/(1.0f + __expf(-x)); }
DEVI float silu_(float x){ return x * sigm(x); }

DEVI void gload16(const u16* gsrc, u16* lds){
  __builtin_amdgcn_global_load_lds(
      (const __attribute__((address_space(1))) unsigned int*)gsrc,
      (__attribute__((address_space(3))) unsigned int*)lds, 16, 0, 0);
}

constexpr int L_=2048, B_=8, D_=1024, Z_=128, H_=2048, N_=16;
constexpr int CH_=128, NC_=16;
constexpr int MXN_=4224;   // 33 * 128 — exact with 128-col tiles

// ---------------- LayerNorm (f32 [L][B][D] -> bf16 [B][L][D]) ----------------
__global__ __launch_bounds__(256) void k_ln(const float* __restrict__ x,
                                            const float* __restrict__ w,
                                            const float* __restrict__ b,
                                            u16* __restrict__ xn){
  int row = blockIdx.x, t = threadIdx.x;
  int l = row >> 3, bb = row & 7;
  const float4* xr = (const float4*)(x + (size_t)row*D_);
  float4 v = xr[t];
  float s  = v.x+v.y+v.z+v.w;
  float sq = v.x*v.x+v.y*v.y+v.z*v.z+v.w*v.w;
  #pragma unroll
  for (int m=1; m<64; m<<=1){ s += __shfl_xor(s, m); sq += __shfl_xor(sq, m); }
  __shared__ float ss[4], sv[4];
  int wv = t>>6;
  if ((t&63)==0){ ss[wv]=s; sv[wv]=sq; }
  __syncthreads();
  s = ss[0]+ss[1]+ss[2]+ss[3]; sq = sv[0]+sv[1]+sv[2]+sv[3];
  float mu = s*(1.0f/D_);
  float var = sq*(1.0f/D_) - mu*mu;
  float rs = rsqrtf(var + 1e-5f);
  float4 wv4 = ((const float4*)w)[t];
  float4 bv4 = ((const float4*)b)[t];
  u16 o0 = f2bf((v.x-mu)*rs*wv4.x+bv4.x);
  u16 o1 = f2bf((v.y-mu)*rs*wv4.y+bv4.y);
  u16 o2 = f2bf((v.z-mu)*rs*wv4.z+bv4.z);
  u16 o3 = f2bf((v.w-mu)*rs*wv4.w+bv4.w);
  *(uint2*)(xn + ((size_t)bb*L_ + l)*D_ + t*4) =
      make_uint2((u32)o0 | ((u32)o1<<16), (u32)o2 | ((u32)o3<<16));
}

// ---------------- weight transpose: f32 [R][C] -> bf16 [C][R] ----------------
__global__ __launch_bounds__(256) void k_tr(const float* __restrict__ in, int R, int C,
                                            u16* __restrict__ out){
  __shared__ u16 TT[32*33];
  int c0 = blockIdx.x*32, r0 = blockIdx.y*32;
  int t = threadIdx.x;
  int lr = t>>3, lc4 = (t&7)*4;
  float4 v = *(const float4*)&in[(size_t)(r0+lr)*C + c0 + lc4];
  TT[(lc4+0)*33 + lr] = f2bf(v.x);
  TT[(lc4+1)*33 + lr] = f2bf(v.y);
  TT[(lc4+2)*33 + lr] = f2bf(v.z);
  TT[(lc4+3)*33 + lr] = f2bf(v.w);
  __syncthreads();
  int orr = t>>3, oc4 = (t&7)*4;
  u16 a0 = TT[orr*33 + oc4+0], a1 = TT[orr*33 + oc4+1];
  u16 a2 = TT[orr*33 + oc4+2], a3 = TT[orr*33 + oc4+3];
  *(uint2*)&out[(size_t)(c0+orr)*R + r0 + oc4] =
      make_uint2((u32)a0 | ((u32)a1<<16), (u32)a2 | ((u32)a3<<16));
}

// ---------------- EMA ----------------
__global__ void k_ema_params(const float* __restrict__ delta, const float* __restrict__ alpha,
                             const float* __restrict__ beta,  const float* __restrict__ gamma,
                             float* __restrict__ qA, float* __restrict__ wcA, float* __restrict__ qPA){
  int i = blockIdx.x*256 + threadIdx.x;
  if (i >= D_*N_) return;
  float p = 1.0f/(1.0f + expf(-delta[i]));
  float q = 1.0f - p*(1.0f/(1.0f + expf(-alpha[i])));
  qA[i]  = q;
  wcA[i] = p*beta[i]*gamma[i]*0.25f;
  qPA[i] = powf(q, (float)CH_);
}

__global__ __launch_bounds__(256) void k_ema_a(const u16* __restrict__ xn,
                                               const float* __restrict__ qA,
                                               float* __restrict__ F){
  int d = blockIdx.x*256 + threadIdx.x;
  int b = blockIdx.y, c = blockIdx.z;
  float q[N_], s[N_];
  #pragma unroll
  for (int n=0;n<N_;n++){ q[n]=qA[d*N_+n]; s[n]=0.0f; }
  for (int t=0;t<CH_;t++){
    int l = c*CH_ + t;
    float x = bf2f(xn[((size_t)b*L_ + l)*D_ + d]);
    #pragma unroll
    for (int n=0;n<N_;n++) s[n] = q[n]*s[n] + x;
  }
  float* Fo = F + (((size_t)c*B_ + b)*D_ + d)*N_;
  #pragma unroll
  for (int n=0;n<N_;n++) Fo[n] = s[n];
}

__global__ __launch_bounds__(256) void k_ema_b(float* __restrict__ F,
                                               const float* __restrict__ qPA){
  int i = blockIdx.x*256 + threadIdx.x;
  int n = i & (N_-1);
  int d = (i>>4) & (D_-1);
  int b = i >> 14;
  float qP = qPA[d*N_+n];
  float S = 0.0f;
  for (int c=0;c<NC_;c++){
    size_t idx = (((size_t)c*B_ + b)*D_ + d)*N_ + n;
    float f = F[idx];
    F[idx] = S;
    S = qP*S + f;
  }
}

__global__ __launch_bounds__(256) void k_ema_c(const u16* __restrict__ xn,
                                               const float* __restrict__ qA,
                                               const float* __restrict__ wcA,
                                               const float* __restrict__ CY,
                                               const float* __restrict__ omega,
                                               u16* __restrict__ mx){
  int d = blockIdx.x*256 + threadIdx.x;
  int b = blockIdx.y, c = blockIdx.z;
  float q[N_], wc[N_], s[N_];
  const float* cy = CY + (((size_t)c*B_ + b)*D_ + d)*N_;
  #pragma unroll
  for (int n=0;n<N_;n++){ q[n]=qA[d*N_+n]; wc[n]=wcA[d*N_+n]; s[n]=cy[n]; }
  float om = omega[d];
  for (int t=0;t<CH_;t++){
    int l = c*CH_ + t;
    float x = bf2f(xn[((size_t)b*L_ + l)*D_ + d]);
    float acc = 0.0f;
    #pragma unroll
    for (int n=0;n<N_;n++){ s[n] = q[n]*s[n] + x; acc += wc[n]*s[n]; }
    mx[((size_t)b*L_ + l)*D_ + d] = f2bf(silu_(acc + x*om));
  }
}

// ======== 128x128-tile 4-wave GEMM, BK=32, 3-buffer single-barrier pipeline =====
// LDS: 3 bufs x (A 8KB + B 8KB) = 48 KiB.  4 loads/thread/K-tile; steady vmcnt(4).
// One s_barrier per K-tile; STG(t+2) issued BEFORE CMP(t) so loads overlap MFMA.
// Packed layout (2 rows per 128B line, conflict-free):
//   dest chunk q (linear) holds A[(q>>3)+(s>>2)*64][(s&3)*8..], s=(q&7)^((q>>3)&7)
//   read row R, k-chunk c -> chunk (R&63)*8 + ((c+(R>>6)*4)^(R&7))   [verified inverse]
#define STG(BUF, K0) do {                                                         \
    int _ab = (BUF)*8192;                                                         \
    _Pragma("unroll")                                                             \
    for (int it=0; it<2; ++it){                                                   \
      int idx = it*256 + tid;                                                     \
      int s = (idx&7) ^ ((idx>>3)&7);                                             \
      int r = (idx>>3) + ((s>>2)<<6);                                             \
      gload16(Ab + (size_t)(rowBase + r)*lda + (K0) + ((s&3)*8),                  \
              &LDS[_ab + idx*8]);                                                 \
    }                                                                             \
    _Pragma("unroll")                                                             \
    for (int it=0; it<2; ++it){                                                   \
      int idx = it*256 + tid;                                                     \
      int s = (idx&7) ^ ((idx>>3)&7);                                             \
      int r = (idx>>3) + ((s>>2)<<6);                                             \
      gload16(Bb + (size_t)(colBase + r)*ldb + (K0) + ((s&3)*8),                  \
              &LDS[_ab + 4096 + idx*8]);                                          \
    }                                                                             \
  } while(0)

#define CMP(BUF) do {                                                             \
    int _ab = (BUF)*8192;                                                         \
    bf16x8_t af[4], bfr[4];                                                       \
    _Pragma("unroll")                                                             \
    for (int m=0;m<4;m++)                                                         \
      af[m]  = *(const bf16x8_t*)&LDS[_ab + (m*16 + lane15)*64 +                  \
                                      ((((lane4 + ah4) ^ l7))<<3)];               \
    _Pragma("unroll")                                                             \
    for (int n=0;n<4;n++)                                                         \
      bfr[n] = *(const bf16x8_t*)&LDS[_ab + 4096 + (n*16 + lane15)*64 +           \
                                      ((((lane4 + bh4) ^ l7))<<3)];               \
    __builtin_amdgcn_s_setprio(1);                                                \
    _Pragma("unroll")                                                             \
    for (int m=0;m<4;m++)                                                         \
      _Pragma("unroll")                                                           \
      for (int n=0;n<4;n++)                                                       \
        acc[m][n] = __builtin_amdgcn_mfma_f32_16x16x32_bf16(af[m], bfr[n], acc[m][n], 0,0,0); \
    __builtin_amdgcn_s_setprio(0);                                                \
  } while(0)

// OP0: VT = silu(acc + biasR[row])   OP1: base split   OP2: attn laplace
// OP3: HR = acc * R                  OP4: out = x + u*(silu(hx+acc+biasC) - x)
template<int OP>
__global__ __launch_bounds__(256) void k_gall(
    const u16* __restrict__ A, int lda, long aStr,
    const u16* __restrict__ Bm, int ldb, long bStr,
    int K,
    u16* __restrict__ C, int ldc, long cStr,
    const float* __restrict__ biasC, const float* __restrict__ biasR,
    const float* __restrict__ relpos,
    const float* __restrict__ qkg, const float* __restrict__ qkb,
    u16* __restrict__ P0, u16* __restrict__ P1,
    u16* __restrict__ P2, u16* __restrict__ P3,
    const u16* __restrict__ RP0, const u16* __restrict__ RP1,
    const float* __restrict__ xin, float* __restrict__ outf, int bb)
{
  __shared__ u16 LDS[24576];   // 48 KiB: 3 bufs of 16 KiB (A@0 B@4096 each, u16)
  int zz = blockIdx.z;
  const u16* Ab = A + (size_t)zz*aStr;
  const u16* Bb = Bm + (size_t)zz*bStr;

  // T1: XCD-aware bijective chunked swizzle per z-slice (gx*gy % 8 == 0)
  int gx = gridDim.x;
  int f = blockIdx.x + gx*blockIdx.y;
  int q8 = (gx*gridDim.y) >> 3;
  int wg = (f & 7)*q8 + (f >> 3);
  int rowBase = (wg / gx)*128;
  int colBase = (wg % gx)*128;

  int tid = threadIdx.x;
  int lane = tid & 63, wave = tid >> 6;
  int wm = (wave>>1)*64, wn = (wave&1)*64;
  int lane15 = lane & 15, lane4 = lane >> 4;
  int ah4 = wm >> 4;        // (wm>>6)*4 : 0 or 4
  int bh4 = wn >> 4;
  int l7  = lane15 & 7;

  f32x4_t acc[4][4];
  #pragma unroll
  for (int m=0;m<4;m++)
    #pragma unroll
    for (int n=0;n<4;n++) acc[m][n] = (f32x4_t){0.f,0.f,0.f,0.f};

  int nt = K >> 5;   // K=128 -> 4, 1024 -> 32, 2048 -> 64
  STG(0, 0);
  STG(1, 32);
  for (int t = 0; t < nt; ++t){
    if (t + 1 < nt) { asm volatile("s_waitcnt vmcnt(4)" ::: "memory"); }
    else            { asm volatile("s_waitcnt vmcnt(0)" ::: "memory"); }
    __builtin_amdgcn_s_barrier();
    __builtin_amdgcn_sched_barrier(0);
    int cb = t % 3;
    if (t + 2 < nt) { int nb = (t+2) % 3; STG(nb, (t+2)*32); }
    CMP(cb);
  }

  u16* Cb  = C  ? C  + (size_t)zz*cStr : nullptr;
  u16* P0b = P0 ? P0 + (size_t)zz*((size_t)L_*D_) : nullptr;
  u16* P1b = P1 ? P1 + (size_t)zz*((size_t)L_*D_) : nullptr;
  u16* P2b = P2 ? P2 + (size_t)zz*((size_t)L_*Z_) : nullptr;
  u16* P3b = P3 ? P3 + (size_t)zz*((size_t)L_*Z_) : nullptr;
  const u16* RP0b = RP0 ? RP0 + (size_t)zz*(OP==3 ? (size_t)L_*H_ : (size_t)L_*D_) : nullptr;
  const u16* RP1b = RP1 ? RP1 + (size_t)zz*((size_t)L_*D_) : nullptr;
  int bglob = bb + zz;

  #pragma unroll
  for (int m=0;m<4;m++) {
    #pragma unroll
    for (int n=0;n<4;n++) {
      int col = colBase + wn + n*16 + lane15;
      #pragma unroll
      for (int r2=0;r2<4;r2++) {
        int row = rowBase + wm + m*16 + lane4*4 + r2;
        float v = acc[m][n][r2];
        if (OP == 0) {
          Cb[(size_t)row*ldc + col] = f2bf(silu_(v + biasR[row]));
        } else if (OP == 1) {
          v += biasC[col];
          if (col < 1024) {
            P0b[(size_t)row*1024 + col] = f2bf(sigm(v));
          } else if (col < 1152) {
            float s = silu_(v);
            int zi = col - 1024;
            P2b[(size_t)row*128 + zi] = f2bf(s*qkg[zi]     + qkb[zi]);
            P3b[(size_t)row*128 + zi] = f2bf(s*qkg[128+zi] + qkb[128+zi]);
          } else if (col < 3200) {
            Cb[(size_t)row*2048 + (col-1152)] = f2bf(silu_(v));
          } else {
            P1b[(size_t)row*1024 + (col-3200)] = f2bf(v);
          }
        } else if (OP == 2) {
          v = v*(1.0f/(float)L_) + relpos[2047 + col - row];
          v = 0.5f*(1.0f + erff((v - 0.707107f)*2.5066282746f));
          Cb[(size_t)row*ldc + col] = f2bf(v);
        } else if (OP == 3) {
          v *= bf2f(RP0b[(size_t)row*ldc + col]);
          Cb[(size_t)row*ldc + col] = f2bf(v);
        } else {   // OP 4
          v += biasC[col];
          float hx = bf2f(RP0b[(size_t)row*1024 + col]);
          float hval = silu_(hx + v);
          size_t gi = ((size_t)row*B_ + bglob)*D_ + col;
          float xv = xin[gi];
          float uu = bf2f(RP1b[(size_t)row*1024 + col]);
          outf[gi] = xv + uu*(hval - xv);
        }
      }
    }
  }
}

extern "C" void kernel_launch(void* const* d_in, const int* in_sizes, int n_in,
                              void* d_out, int out_size, void* d_ws, size_t ws_size,
                              hipStream_t stream) {
  const float* x      = (const float*)d_in[0];
  const float* delta  = (const float*)d_in[1];
  const float* alpha  = (const float*)d_in[2];
  const float* betaE  = (const float*)d_in[3];
  const float* gammaE = (const float*)d_in[4];
  const float* omega  = (const float*)d_in[5];
  const float* v_w    = (const float*)d_in[6];
  const float* v_b    = (const float*)d_in[7];
  const float* mx_w   = (const float*)d_in[8];
  const float* mx_b   = (const float*)d_in[9];
  const float* h_w    = (const float*)d_in[10];
  const float* h_b    = (const float*)d_in[11];
  const float* qkg    = (const float*)d_in[12];
  const float* qkb    = (const float*)d_in[13];
  const float* relpos = (const float*)d_in[14];
  const float* ln_w   = (const float*)d_in[15];
  const float* ln_b   = (const float*)d_in[16];
  float* out = (float*)d_out;

  const size_t fixedB = 92733440ull;
  const size_t perNB  = 42991616ull;
  int NB = 8;
  while (NB > 1 && fixedB + (size_t)NB*perNB > ws_size) NB >>= 1;
  int NG = B_ / NB;

  char* ws = (char*)d_ws;
  size_t o = 0;
  auto alloc = [&](size_t sz){ size_t r = o; o += sz; return r; };
  u16* XN    = (u16*)(ws + alloc(33554432));            // [B][L][D]
  u16* MX    = (u16*)(ws + alloc(33554432));            // [B][L][D]
  u16* VWT   = (u16*)(ws + alloc(4194304));             // [H][D]
  u16* MXWT  = (u16*)(ws + alloc((size_t)MXN_*D_*2));   // [4224][D]
  u16* HWT   = (u16*)(ws + alloc(4194304));             // [D][H]
  float* EQ  = (float*)(ws + alloc(65536));
  float* EW  = (float*)(ws + alloc(65536));
  float* EP  = (float*)(ws + alloc(65536));
  float* Ff  = (float*)(ws + alloc(8388608));
  u16* VT    = (u16*)(ws + alloc((size_t)NB*8388608));   // [NB][H][L]
  u16* ATTN  = (u16*)(ws + alloc((size_t)NB*8388608));   // [NB][L][L]
  u16* Rb    = (u16*)(ws + alloc((size_t)NB*8388608));   // [NB][L][H]
  u16* HRb   = (u16*)(ws + alloc((size_t)NB*8388608));   // [NB][L][H]
  u16* Ub    = (u16*)(ws + alloc((size_t)NB*4194304));   // [NB][L][D]
  u16* HXb   = (u16*)(ws + alloc((size_t)NB*4194304));   // [NB][L][D]
  u16* Qb    = (u16*)(ws + alloc((size_t)NB*524288));    // [NB][L][Z]
  u16* Kb    = (u16*)(ws + alloc((size_t)NB*524288));    // [NB][L][Z]

  // 1. LayerNorm -> XN [B][L][D]
  k_ln<<<L_*B_, 256, 0, stream>>>(x, ln_w, ln_b, XN);
  // 2. EMA blocked scan -> MX [B][L][D]
  k_ema_params<<<(D_*N_+255)/256, 256, 0, stream>>>(delta, alpha, betaE, gammaE, EQ, EW, EP);
  k_ema_a<<<dim3(D_/256, B_, NC_), 256, 0, stream>>>(XN, EQ, Ff);
  k_ema_b<<<(B_*D_*N_)/256, 256, 0, stream>>>(Ff, EP);
  k_ema_c<<<dim3(D_/256, B_, NC_), 256, 0, stream>>>(XN, EQ, EW, Ff, omega, MX);
  // 3. weight transposes
  k_tr<<<dim3(H_/32, D_/32), 256, 0, stream>>>(v_w, D_, H_, VWT);
  k_tr<<<dim3(MXN_/32, D_/32), 256, 0, stream>>>(mx_w, D_, MXN_, MXWT);
  k_tr<<<dim3(D_/32, H_/32), 256, 0, stream>>>(h_w, H_, D_, HWT);

  // 4. grouped per-batch pipeline
  for (int g = 0; g < NG; ++g) {
    int b0 = g*NB;
    // VT[z][h][l] = silu(VWT @ XN_b^T + v_b[h])      M=H, N=L, K=D
    k_gall<0><<<dim3(L_/128, H_/128, NB), 256, 0, stream>>>(
        VWT, D_, 0L, XN + (size_t)b0*L_*D_, D_, (long)L_*D_, D_,
        VT, L_, (long)H_*L_,
        nullptr, v_b, nullptr, nullptr, nullptr,
        nullptr, nullptr, nullptr, nullptr,
        nullptr, nullptr, nullptr, nullptr, 0);
    // base split                                      M=L, N=4224, K=D
    k_gall<1><<<dim3(MXN_/128, L_/128, NB), 256, 0, stream>>>(
        MX + (size_t)b0*L_*D_, D_, (long)L_*D_, MXWT, D_, 0L, D_,
        Rb, H_, (long)L_*H_,
        mx_b, nullptr, nullptr, qkg, qkb,
        Ub, HXb, Qb, Kb,
        nullptr, nullptr, nullptr, nullptr, 0);
    // attn = laplace(Q K^T / L + relbias)             M=L, N=L, K=Z
    k_gall<2><<<dim3(L_/128, L_/128, NB), 256, 0, stream>>>(
        Qb, Z_, (long)L_*Z_, Kb, Z_, (long)L_*Z_, Z_,
        ATTN, L_, (long)L_*L_,
        nullptr, nullptr, relpos, nullptr, nullptr,
        nullptr, nullptr, nullptr, nullptr,
        nullptr, nullptr, nullptr, nullptr, 0);
    // HR = (attn @ V) * R                             M=L, N=H, K=L
    k_gall<3><<<dim3(H_/128, L_/128, NB), 256, 0, stream>>>(
        ATTN, L_, (long)L_*L_, VT, L_, (long)H_*L_, L_,
        HRb, H_, (long)L_*H_,
        nullptr, nullptr, nullptr, nullptr, nullptr,
        nullptr, nullptr, nullptr, nullptr,
        Rb, nullptr, nullptr, nullptr, 0);
    // out = x + u*(silu(hx + HR @ h_w + h_b) - x)     M=L, N=D, K=H
    k_gall<4><<<dim3(D_/128, L_/128, NB), 256, 0, stream>>>(
        HRb, H_, (long)L_*H_, HWT, H_, 0L, H_,
        nullptr, 0, 0L,
        h_b, nullptr, nullptr, nullptr, nullptr,
        nullptr, nullptr, nullptr, nullptr,
        HXb, Ub, x, out, b0);
  }
}

// Round 17
// 741.162 us; speedup vs baseline: 1.1185x; 1.1185x over previous
//
#include <hip/hip_runtime.h>
#include <hip/hip_bf16.h>
#include <math.h>

typedef unsigned short u16;
typedef unsigned int   u32;
typedef __bf16 bf16x8_t __attribute__((ext_vector_type(8)));
typedef float  f32x4_t  __attribute__((ext_vector_type(4)));

#define DEVI static __device__ __forceinline__

DEVI float bf2f(u16 u){ union{u32 i; float f;} v; v.i = ((u32)u)<<16; return v.f; }
DEVI u16 f2bf(float f){ union{float f; u32 i;} v; v.f = f; u32 i = v.i; i += 0x7fffu + ((i>>16)&1u); return (u16)(i>>16); }
DEVI float sigm(float x){ return 1.0f/(1.0f + __expf(-x)); }
DEVI float silu_(float x){ return x * sigm(x); }

DEVI void gload16(const u16* gsrc, u16* lds){
  __builtin_amdgcn_global_load_lds(
      (const __attribute__((address_space(1))) unsigned int*)gsrc,
      (__attribute__((address_space(3))) unsigned int*)lds, 16, 0, 0);
}

constexpr int L_=2048, B_=8, D_=1024, Z_=128, H_=2048, N_=16;
constexpr int CH_=128, NC_=16;
constexpr int MXN_=4224;   // 33 * 128 — exact with 128-col tiles

// ---------------- LayerNorm (f32 [L][B][D] -> bf16 [B][L][D]) ----------------
__global__ __launch_bounds__(256) void k_ln(const float* __restrict__ x,
                                            const float* __restrict__ w,
                                            const float* __restrict__ b,
                                            u16* __restrict__ xn){
  int row = blockIdx.x, t = threadIdx.x;
  int l = row >> 3, bb = row & 7;
  const float4* xr = (const float4*)(x + (size_t)row*D_);
  float4 v = xr[t];
  float s  = v.x+v.y+v.z+v.w;
  float sq = v.x*v.x+v.y*v.y+v.z*v.z+v.w*v.w;
  #pragma unroll
  for (int m=1; m<64; m<<=1){ s += __shfl_xor(s, m); sq += __shfl_xor(sq, m); }
  __shared__ float ss[4], sv[4];
  int wv = t>>6;
  if ((t&63)==0){ ss[wv]=s; sv[wv]=sq; }
  __syncthreads();
  s = ss[0]+ss[1]+ss[2]+ss[3]; sq = sv[0]+sv[1]+sv[2]+sv[3];
  float mu = s*(1.0f/D_);
  float var = sq*(1.0f/D_) - mu*mu;
  float rs = rsqrtf(var + 1e-5f);
  float4 wv4 = ((const float4*)w)[t];
  float4 bv4 = ((const float4*)b)[t];
  u16 o0 = f2bf((v.x-mu)*rs*wv4.x+bv4.x);
  u16 o1 = f2bf((v.y-mu)*rs*wv4.y+bv4.y);
  u16 o2 = f2bf((v.z-mu)*rs*wv4.z+bv4.z);
  u16 o3 = f2bf((v.w-mu)*rs*wv4.w+bv4.w);
  *(uint2*)(xn + ((size_t)bb*L_ + l)*D_ + t*4) =
      make_uint2((u32)o0 | ((u32)o1<<16), (u32)o2 | ((u32)o3<<16));
}

// ---------------- weight transpose: f32 [R][C] -> bf16 [C][R] ----------------
__global__ __launch_bounds__(256) void k_tr(const float* __restrict__ in, int R, int C,
                                            u16* __restrict__ out){
  __shared__ u16 TT[32*33];
  int c0 = blockIdx.x*32, r0 = blockIdx.y*32;
  int t = threadIdx.x;
  int lr = t>>3, lc4 = (t&7)*4;
  float4 v = *(const float4*)&in[(size_t)(r0+lr)*C + c0 + lc4];
  TT[(lc4+0)*33 + lr] = f2bf(v.x);
  TT[(lc4+1)*33 + lr] = f2bf(v.y);
  TT[(lc4+2)*33 + lr] = f2bf(v.z);
  TT[(lc4+3)*33 + lr] = f2bf(v.w);
  __syncthreads();
  int orr = t>>3, oc4 = (t&7)*4;
  u16 a0 = TT[orr*33 + oc4+0], a1 = TT[orr*33 + oc4+1];
  u16 a2 = TT[orr*33 + oc4+2], a3 = TT[orr*33 + oc4+3];
  *(uint2*)&out[(size_t)(c0+orr)*R + r0 + oc4] =
      make_uint2((u32)a0 | ((u32)a1<<16), (u32)a2 | ((u32)a3<<16));
}

// ---------------- EMA ----------------
__global__ void k_ema_params(const float* __restrict__ delta, const float* __restrict__ alpha,
                             const float* __restrict__ beta,  const float* __restrict__ gamma,
                             float* __restrict__ qA, float* __restrict__ wcA, float* __restrict__ qPA){
  int i = blockIdx.x*256 + threadIdx.x;
  if (i >= D_*N_) return;
  float p = 1.0f/(1.0f + expf(-delta[i]));
  float q = 1.0f - p*(1.0f/(1.0f + expf(-alpha[i])));
  qA[i]  = q;
  wcA[i] = p*beta[i]*gamma[i]*0.25f;
  qPA[i] = powf(q, (float)CH_);
}

__global__ __launch_bounds__(256) void k_ema_a(const u16* __restrict__ xn,
                                               const float* __restrict__ qA,
                                               float* __restrict__ F){
  int d = blockIdx.x*256 + threadIdx.x;
  int b = blockIdx.y, c = blockIdx.z;
  float q[N_], s[N_];
  #pragma unroll
  for (int n=0;n<N_;n++){ q[n]=qA[d*N_+n]; s[n]=0.0f; }
  for (int t=0;t<CH_;t++){
    int l = c*CH_ + t;
    float x = bf2f(xn[((size_t)b*L_ + l)*D_ + d]);
    #pragma unroll
    for (int n=0;n<N_;n++) s[n] = q[n]*s[n] + x;
  }
  float* Fo = F + (((size_t)c*B_ + b)*D_ + d)*N_;
  #pragma unroll
  for (int n=0;n<N_;n++) Fo[n] = s[n];
}

__global__ __launch_bounds__(256) void k_ema_b(float* __restrict__ F,
                                               const float* __restrict__ qPA){
  int i = blockIdx.x*256 + threadIdx.x;
  int n = i & (N_-1);
  int d = (i>>4) & (D_-1);
  int b = i >> 14;
  float qP = qPA[d*N_+n];
  float S = 0.0f;
  for (int c=0;c<NC_;c++){
    size_t idx = (((size_t)c*B_ + b)*D_ + d)*N_ + n;
    float f = F[idx];
    F[idx] = S;
    S = qP*S + f;
  }
}

__global__ __launch_bounds__(256) void k_ema_c(const u16* __restrict__ xn,
                                               const float* __restrict__ qA,
                                               const float* __restrict__ wcA,
                                               const float* __restrict__ CY,
                                               const float* __restrict__ omega,
                                               u16* __restrict__ mx){
  int d = blockIdx.x*256 + threadIdx.x;
  int b = blockIdx.y, c = blockIdx.z;
  float q[N_], wc[N_], s[N_];
  const float* cy = CY + (((size_t)c*B_ + b)*D_ + d)*N_;
  #pragma unroll
  for (int n=0;n<N_;n++){ q[n]=qA[d*N_+n]; wc[n]=wcA[d*N_+n]; s[n]=cy[n]; }
  float om = omega[d];
  for (int t=0;t<CH_;t++){
    int l = c*CH_ + t;
    float x = bf2f(xn[((size_t)b*L_ + l)*D_ + d]);
    float acc = 0.0f;
    #pragma unroll
    for (int n=0;n<N_;n++){ s[n] = q[n]*s[n] + x; acc += wc[n]*s[n]; }
    mx[((size_t)b*L_ + l)*D_ + d] = f2bf(silu_(acc + x*om));
  }
}

// ======== 128x128-tile 4-wave GEMM, BK=64, 2-buffer counted-vmcnt + XOR swizzle ==
// (measured optimum: 2 blocks/CU, 0 bank conflicts, T1 XCD swizzle)
#define STG(BUF, K0) do {                                                         \
    int _ab = (BUF)*16384;                                                        \
    _Pragma("unroll")                                                             \
    for (int it=0; it<4; ++it){                                                   \
      int idx = it*256 + tid; int r = idx>>3, ch = idx&7;                         \
      gload16(Ab + (size_t)(rowBase + r)*lda + (K0) + ((ch ^ (r&7))*8),           \
              &LDS[_ab + idx*8]);                                                 \
    }                                                                             \
    _Pragma("unroll")                                                             \
    for (int it=0; it<4; ++it){                                                   \
      int idx = it*256 + tid; int r = idx>>3, ch = idx&7;                         \
      gload16(Bb + (size_t)(colBase + r)*ldb + (K0) + ((ch ^ (r&7))*8),           \
              &LDS[_ab + 8192 + idx*8]);                                          \
    }                                                                             \
  } while(0)

#define CMP(BUF) do {                                                             \
    int _ab = (BUF)*16384;                                                        \
    _Pragma("unroll")                                                             \
    for (int ks=0; ks<2; ++ks){                                                   \
      bf16x8_t af[4], bfr[4];                                                     \
      int kfx = (ks*32 + lane4*8) ^ ((lane15&7)<<3);                              \
      _Pragma("unroll")                                                           \
      for (int m=0;m<4;m++)                                                       \
        af[m]  = *(const bf16x8_t*)&LDS[_ab + (wm + m*16 + lane15)*64 + kfx];     \
      _Pragma("unroll")                                                           \
      for (int n=0;n<4;n++)                                                       \
        bfr[n] = *(const bf16x8_t*)&LDS[_ab + 8192 + (wn + n*16 + lane15)*64 + kfx]; \
      __builtin_amdgcn_s_setprio(1);                                              \
      _Pragma("unroll")                                                           \
      for (int m=0;m<4;m++)                                                       \
        _Pragma("unroll")                                                         \
        for (int n=0;n<4;n++)                                                     \
          acc[m][n] = __builtin_amdgcn_mfma_f32_16x16x32_bf16(af[m], bfr[n], acc[m][n], 0,0,0); \
      __builtin_amdgcn_s_setprio(0);                                              \
    }                                                                             \
  } while(0)

// OP0: VT = silu(acc + biasR[row])   OP1: base split   OP2: attn laplace
// OP3: HR = acc * R                  OP4: out = x + u*(silu(hx+acc+biasC) - x)
template<int OP>
__global__ __launch_bounds__(256) void k_gall(
    const u16* __restrict__ A, int lda, long aStr,
    const u16* __restrict__ Bm, int ldb, long bStr,
    int K,
    u16* __restrict__ C, int ldc, long cStr,
    const float* __restrict__ biasC, const float* __restrict__ biasR,
    const float* __restrict__ relpos,
    const float* __restrict__ qkg, const float* __restrict__ qkb,
    u16* __restrict__ P0, u16* __restrict__ P1,
    u16* __restrict__ P2, u16* __restrict__ P3,
    const u16* __restrict__ RP0, const u16* __restrict__ RP1,
    const float* __restrict__ xin, float* __restrict__ outf, int bb)
{
  __shared__ u16 LDS[32768];   // 64 KiB: buf0 A@0 B@8192, buf1 A@16384 B@24576
  int zz = blockIdx.z;
  const u16* Ab = A + (size_t)zz*aStr;
  const u16* Bb = Bm + (size_t)zz*bStr;

  // T1: XCD-aware bijective chunked swizzle per z-slice (gx*gy % 8 == 0)
  int gx = gridDim.x;
  int f = blockIdx.x + gx*blockIdx.y;
  int q8 = (gx*gridDim.y) >> 3;
  int wg = (f & 7)*q8 + (f >> 3);
  int rowBase = (wg / gx)*128;
  int colBase = (wg % gx)*128;

  int tid = threadIdx.x;
  int lane = tid & 63, wave = tid >> 6;
  int wm = (wave>>1)*64, wn = (wave&1)*64;
  int lane15 = lane & 15, lane4 = lane >> 4;

  f32x4_t acc[4][4];
  #pragma unroll
  for (int m=0;m<4;m++)
    #pragma unroll
    for (int n=0;n<4;n++) acc[m][n] = (f32x4_t){0.f,0.f,0.f,0.f};

  int nt = K >> 6;   // >= 2 for all our shapes (K=128,1024,2048)
  STG(0, 0);
  STG(1, 64);
  for (int t = 0; t < nt; ++t){
    if (t + 1 < nt) { asm volatile("s_waitcnt vmcnt(8)" ::: "memory"); }
    else            { asm volatile("s_waitcnt vmcnt(0)" ::: "memory"); }
    __builtin_amdgcn_s_barrier();
    __builtin_amdgcn_sched_barrier(0);
    CMP(t & 1);
    if (t + 2 < nt) {
      __builtin_amdgcn_s_barrier();          // all waves done reading buf (t&1)
      STG(t & 1, (t+2)*64);
    }
  }

  u16* Cb  = C  ? C  + (size_t)zz*cStr : nullptr;
  u16* P0b = P0 ? P0 + (size_t)zz*((size_t)L_*D_) : nullptr;
  u16* P1b = P1 ? P1 + (size_t)zz*((size_t)L_*D_) : nullptr;
  u16* P2b = P2 ? P2 + (size_t)zz*((size_t)L_*Z_) : nullptr;
  u16* P3b = P3 ? P3 + (size_t)zz*((size_t)L_*Z_) : nullptr;
  const u16* RP0b = RP0 ? RP0 + (size_t)zz*(OP==3 ? (size_t)L_*H_ : (size_t)L_*D_) : nullptr;
  const u16* RP1b = RP1 ? RP1 + (size_t)zz*((size_t)L_*D_) : nullptr;
  int bglob = bb + zz;

  #pragma unroll
  for (int m=0;m<4;m++) {
    #pragma unroll
    for (int n=0;n<4;n++) {
      int col = colBase + wn + n*16 + lane15;
      #pragma unroll
      for (int r2=0;r2<4;r2++) {
        int row = rowBase + wm + m*16 + lane4*4 + r2;
        float v = acc[m][n][r2];
        if (OP == 0) {
          Cb[(size_t)row*ldc + col] = f2bf(silu_(v + biasR[row]));
        } else if (OP == 1) {
          v += biasC[col];
          if (col < 1024) {
            P0b[(size_t)row*1024 + col] = f2bf(sigm(v));
          } else if (col < 1152) {
            float s = silu_(v);
            int zi = col - 1024;
            P2b[(size_t)row*128 + zi] = f2bf(s*qkg[zi]     + qkb[zi]);
            P3b[(size_t)row*128 + zi] = f2bf(s*qkg[128+zi] + qkb[128+zi]);
          } else if (col < 3200) {
            Cb[(size_t)row*2048 + (col-1152)] = f2bf(silu_(v));
          } else {
            P1b[(size_t)row*1024 + (col-3200)] = f2bf(v);
          }
        } else if (OP == 2) {
          v = v*(1.0f/(float)L_) + relpos[2047 + col - row];
          v = 0.5f*(1.0f + erff((v - 0.707107f)*2.5066282746f));
          Cb[(size_t)row*ldc + col] = f2bf(v);
        } else if (OP == 3) {
          v *= bf2f(RP0b[(size_t)row*ldc + col]);
          Cb[(size_t)row*ldc + col] = f2bf(v);
        } else {   // OP 4
          v += biasC[col];
          float hx = bf2f(RP0b[(size_t)row*1024 + col]);
          float hval = silu_(hx + v);
          size_t gi = ((size_t)row*B_ + bglob)*D_ + col;
          float xv = xin[gi];
          float uu = bf2f(RP1b[(size_t)row*1024 + col]);
          outf[gi] = xv + uu*(hval - xv);
        }
      }
    }
  }
}

extern "C" void kernel_launch(void* const* d_in, const int* in_sizes, int n_in,
                              void* d_out, int out_size, void* d_ws, size_t ws_size,
                              hipStream_t stream) {
  const float* x      = (const float*)d_in[0];
  const float* delta  = (const float*)d_in[1];
  const float* alpha  = (const float*)d_in[2];
  const float* betaE  = (const float*)d_in[3];
  const float* gammaE = (const float*)d_in[4];
  const float* omega  = (const float*)d_in[5];
  const float* v_w    = (const float*)d_in[6];
  const float* v_b    = (const float*)d_in[7];
  const float* mx_w   = (const float*)d_in[8];
  const float* mx_b   = (const float*)d_in[9];
  const float* h_w    = (const float*)d_in[10];
  const float* h_b    = (const float*)d_in[11];
  const float* qkg    = (const float*)d_in[12];
  const float* qkb    = (const float*)d_in[13];
  const float* relpos = (const float*)d_in[14];
  const float* ln_w   = (const float*)d_in[15];
  const float* ln_b   = (const float*)d_in[16];
  float* out = (float*)d_out;

  const size_t fixedB = 92733440ull;
  const size_t perNB  = 42991616ull;
  int NB = 8;
  while (NB > 1 && fixedB + (size_t)NB*perNB > ws_size) NB >>= 1;
  int NG = B_ / NB;

  char* ws = (char*)d_ws;
  size_t o = 0;
  auto alloc = [&](size_t sz){ size_t r = o; o += sz; return r; };
  u16* XN    = (u16*)(ws + alloc(33554432));            // [B][L][D]
  u16* MX    = (u16*)(ws + alloc(33554432));            // [B][L][D]
  u16* VWT   = (u16*)(ws + alloc(4194304));             // [H][D]
  u16* MXWT  = (u16*)(ws + alloc((size_t)MXN_*D_*2));   // [4224][D]
  u16* HWT   = (u16*)(ws + alloc(4194304));             // [D][H]
  float* EQ  = (float*)(ws + alloc(65536));
  float* EW  = (float*)(ws + alloc(65536));
  float* EP  = (float*)(ws + alloc(65536));
  float* Ff  = (float*)(ws + alloc(8388608));
  u16* VT    = (u16*)(ws + alloc((size_t)NB*8388608));   // [NB][H][L]
  u16* ATTN  = (u16*)(ws + alloc((size_t)NB*8388608));   // [NB][L][L]
  u16* Rb    = (u16*)(ws + alloc((size_t)NB*8388608));   // [NB][L][H]
  u16* HRb   = (u16*)(ws + alloc((size_t)NB*8388608));   // [NB][L][H]
  u16* Ub    = (u16*)(ws + alloc((size_t)NB*4194304));   // [NB][L][D]
  u16* HXb   = (u16*)(ws + alloc((size_t)NB*4194304));   // [NB][L][D]
  u16* Qb    = (u16*)(ws + alloc((size_t)NB*524288));    // [NB][L][Z]
  u16* Kb    = (u16*)(ws + alloc((size_t)NB*524288));    // [NB][L][Z]

  // 1. LayerNorm -> XN [B][L][D]
  k_ln<<<L_*B_, 256, 0, stream>>>(x, ln_w, ln_b, XN);
  // 2. EMA blocked scan -> MX [B][L][D]
  k_ema_params<<<(D_*N_+255)/256, 256, 0, stream>>>(delta, alpha, betaE, gammaE, EQ, EW, EP);
  k_ema_a<<<dim3(D_/256, B_, NC_), 256, 0, stream>>>(XN, EQ, Ff);
  k_ema_b<<<(B_*D_*N_)/256, 256, 0, stream>>>(Ff, EP);
  k_ema_c<<<dim3(D_/256, B_, NC_), 256, 0, stream>>>(XN, EQ, EW, Ff, omega, MX);
  // 3. weight transposes
  k_tr<<<dim3(H_/32, D_/32), 256, 0, stream>>>(v_w, D_, H_, VWT);
  k_tr<<<dim3(MXN_/32, D_/32), 256, 0, stream>>>(mx_w, D_, MXN_, MXWT);
  k_tr<<<dim3(D_/32, H_/32), 256, 0, stream>>>(h_w, H_, D_, HWT);

  // 4. grouped per-batch pipeline
  for (int g = 0; g < NG; ++g) {
    int b0 = g*NB;
    // VT[z][h][l] = silu(VWT @ XN_b^T + v_b[h])      M=H, N=L, K=D
    k_gall<0><<<dim3(L_/128, H_/128, NB), 256, 0, stream>>>(
        VWT, D_, 0L, XN + (size_t)b0*L_*D_, D_, (long)L_*D_, D_,
        VT, L_, (long)H_*L_,
        nullptr, v_b, nullptr, nullptr, nullptr,
        nullptr, nullptr, nullptr, nullptr,
        nullptr, nullptr, nullptr, nullptr, 0);
    // base split                                      M=L, N=4224, K=D
    k_gall<1><<<dim3(MXN_/128, L_/128, NB), 256, 0, stream>>>(
        MX + (size_t)b0*L_*D_, D_, (long)L_*D_, MXWT, D_, 0L, D_,
        Rb, H_, (long)L_*H_,
        mx_b, nullptr, nullptr, qkg, qkb,
        Ub, HXb, Qb, Kb,
        nullptr, nullptr, nullptr, nullptr, 0);
    // attn = laplace(Q K^T / L + relbias)             M=L, N=L, K=Z
    k_gall<2><<<dim3(L_/128, L_/128, NB), 256, 0, stream>>>(
        Qb, Z_, (long)L_*Z_, Kb, Z_, (long)L_*Z_, Z_,
        ATTN, L_, (long)L_*L_,
        nullptr, nullptr, relpos, nullptr, nullptr,
        nullptr, nullptr, nullptr, nullptr,
        nullptr, nullptr, nullptr, nullptr, 0);
    // HR = (attn @ V) * R                             M=L, N=H, K=L
    k_gall<3><<<dim3(H_/128, L_/128, NB), 256, 0, stream>>>(
        ATTN, L_, (long)L_*L_, VT, L_, (long)H_*L_, L_,
        HRb, H_, (long)L_*H_,
        nullptr, nullptr, nullptr, nullptr, nullptr,
        nullptr, nullptr, nullptr, nullptr,
        Rb, nullptr, nullptr, nullptr, 0);
    // out = x + u*(silu(hx + HR @ h_w + h_b) - x)     M=L, N=D, K=H
    k_gall<4><<<dim3(D_/128, L_/128, NB), 256, 0, stream>>>(
        HRb, H_, (long)L_*H_, HWT, H_, 0L, H_,
        nullptr, 0, 0L,
        h_b, nullptr, nullptr, nullptr, nullptr,
        nullptr, nullptr, nullptr, nullptr,
        HXb, Ub, x, out, b0);
  }
}